// Round 15
// baseline (1235.920 us; speedup 1.0000x reference)
//
#include <hip/hip_runtime.h>
#include <hip/hip_bf16.h>

// LSTM B=256,T=512,I=64,H=256. 64 WGs x 1024 thr (16 waves), 4-way j-split.
// Round 15 = r8 skeleton + r11's lane-local gates (weight permutation +
// ds_swizzle transpose; no gl round-trip) + LDS-staged COALESCED republish
// (fixes r11's scattered-publish regression). 2 barriers/step, act dbuf.

#define B_TOT 256
#define T_SEQ 512
#define NIN   64
#define HID   256
#define CHUNK 16
#define JSL   64            // j per WG (4-way split)
#define ROWB  768           // LDS act row stride bytes (320 f16 = 640B data)
#define NKK   10            // K = 320 = 10*32
#define NWG   64

typedef _Float16 half8 __attribute__((ext_vector_type(8)));
typedef float    f32x4 __attribute__((ext_vector_type(4)));
typedef unsigned u32x4 __attribute__((ext_vector_type(4)));

__device__ __forceinline__ float fast_rcp(float x){ return __builtin_amdgcn_rcpf(x); }
__device__ __forceinline__ float sigf(float v){ return fast_rcp(1.0f+__expf(-v)); }
__device__ __forceinline__ float tanhf_fast(float v){ return 1.0f-2.0f*fast_rcp(__expf(2.0f*v)+1.0f); }
__device__ __forceinline__ unsigned short f2h_bits(float f){
    _Float16 h=(_Float16)f; return __builtin_bit_cast(unsigned short,h);
}
template<int IMM>
__device__ __forceinline__ float swz(float v){
    return __builtin_bit_cast(float,
        __builtin_amdgcn_ds_swizzle(__builtin_bit_cast(int, v), IMM));
}

__global__ void __launch_bounds__(1024, 4)
lstm_scan(const float* __restrict__ x,
          const float* __restrict__ Wih,
          const float* __restrict__ Whh,
          const float* __restrict__ bih,
          const float* __restrict__ bhh,
          const float* __restrict__ Wfc,
          const float* __restrict__ bfc,
          float* __restrict__ out,
          unsigned* __restrict__ hq)    // [2][B_TOT][HID] tagged h words
{
    __shared__ __align__(16) char act[2][CHUNK*ROWB];  // dbuf, swizzled

    const int tid  = threadIdx.x;
    const int w    = tid >> 6;       // wave 0..15 = j4-block owner
    const int lane = tid & 63;
    const int lr   = lane & 15;
    const int kg   = lane >> 4;
    const int q4   = lr >> 2;        // gate index of this B-col
    const int j4   = lr & 3;         // j within the 4-block
    const int chunk= blockIdx.x & 15;
    const int jw   = blockIdx.x >> 4;    // 0..3
    const int cb   = chunk*CHUNK;

    // r11 weight permutation: wave w owns ALL 4 gates of j = jw*64 + w*4 + j4
    const int n    = q4*HID + jw*JSL + w*4 + j4;
    const int prow = kg*4 + q4;      // cell-phase batch row of this lane
    const int pj   = w*4 + j4;       // cell-phase j-local of this lane

    // ---- register-resident weight fragments (B operand), 40 VGPRs ----
    half8 wv[NKK];
    const float bias = bih[n] + bhh[n];
    #pragma unroll
    for (int kk = 0; kk < 2; ++kk)
        #pragma unroll
        for (int jj = 0; jj < 8; ++jj)
            wv[kk][jj] = (_Float16)Wih[n*NIN + kk*32 + kg*8 + jj];
    #pragma unroll
    for (int kk = 2; kk < NKK; ++kk)
        #pragma unroll
        for (int jj = 0; jj < 8; ++jj)
            wv[kk][jj] = (_Float16)Whh[n*HID + kk*32 + kg*8 + jj - NIN];

    // ---- init both act buffers: zeros (h_0 = 0), x_0 into buf 0 ----
    for (int i = tid; i < 2*CHUNK*ROWB/4; i += 1024) ((int*)act)[i] = 0;
    __syncthreads();
    {
        float x0 = x[((size_t)(cb + w)*T_SEQ + 0)*NIN + lane];
        *(unsigned short*)(act[0] + w*ROWB + ((lane*2) ^ (w << 4))) = f2h_bits(x0);
    }
    __syncthreads();

    float cst = 0.f, hlast = 0.f;

    // poll roles (r8): wave w polls row w; lane = (partner gp, 16B chunk gq)
    const int gp  = lane >> 4, gq = lane & 15;
    const int gpj = (jw + 1 + gp) & 3;

    for (int t = 0; t < T_SEQ; ++t) {
        const char* acur = act[t & 1];
        char*       anx  = act[(t & 1) ^ 1];

        // prefetch x_{t+1} (plain load; consumed before any poll asm)
        const int tn = (t+1 < T_SEQ) ? t+1 : T_SEQ-1;
        const float xv = x[((size_t)(cb + w)*T_SEQ + tn)*NIN + lane];

        // A fragments from acur (row lr, swizzled, conflict-free)
        half8 af[NKK];
        #pragma unroll
        for (int kk = 0; kk < NKK; ++kk) {
            const int off = (kk*64 + kg*16) ^ (lr << 4);
            af[kk] = *(const half8*)(acur + lr*ROWB + off);
        }
        f32x4 aca = {bias, bias, bias, bias};
        f32x4 acb = {0.f, 0.f, 0.f, 0.f};
        #pragma unroll
        for (int kk = 0; kk < NKK; kk += 2) {
            aca = __builtin_amdgcn_mfma_f32_16x16x32_f16(af[kk],   wv[kk],   aca, 0, 0, 0);
            acb = __builtin_amdgcn_mfma_f32_16x16x32_f16(af[kk+1], wv[kk+1], acb, 0, 0, 0);
        }
        const f32x4 acc = aca + acb;

        // in-wave gate transpose (r11-proven): lane (kg,q4,j4) gathers all 4
        // gates of (row=kg*4+q4, j=w*4+j4). and=0x13 keeps bits{0,1,4};
        // or=g<<2 selects the source gate column group.
        float gate[4];
        #pragma unroll
        for (int r = 0; r < 4; ++r) {
            const float g0 = swz<0x013>(acc[r]);
            const float g1 = swz<0x093>(acc[r]);
            const float g2 = swz<0x113>(acc[r]);
            const float g3 = swz<0x193>(acc[r]);
            if (q4 == r) { gate[0]=g0; gate[1]=g1; gate[2]=g2; gate[3]=g3; }
        }

        // cell update: lane owns (prow, j = jw*64 + pj)
        const float iv = sigf(gate[0]);
        const float fv = sigf(gate[1]);
        const float gv = tanhf_fast(gate[2]);
        const float ov = sigf(gate[3]);
        const float cc = fv*cst + iv*gv;
        cst = cc;
        const float hv = ov*tanhf_fast(cc);
        hlast = hv;
        const unsigned short h16 = f2h_bits(hv);

        // stage own h into act_next (scattered u16 -- also next step's input)
        {
            const int c = NIN + jw*JSL + pj;
            *(unsigned short*)(anx + prow*ROWB + ((c*2) ^ (prow << 4))) = h16;
            if (t < T_SEQ-1)
                *(unsigned short*)(anx + w*ROWB + ((lane*2) ^ (w << 4))) = f2h_bits(xv);
        }
        __syncthreads();   // B1: all h(t+1) staged in anx

        const unsigned tgt = (unsigned)(t+1);
        unsigned* hb = hq + ((size_t)(tgt & 1u)*B_TOT + (cb + w))*HID;

        // republish COALESCED (r8 shape): wave w reads row w's 64 h from LDS,
        // one u32 atomicExch per lane -> 256B contiguous run per wave
        {
            const int c = NIN + jw*JSL + lane;
            const unsigned short hwd =
                *(const unsigned short*)(anx + w*ROWB + ((c*2) ^ (w << 4)));
            (void)__hip_atomic_exchange(hb + jw*JSL + lane,
                                        (tgt << 16) | (unsigned)hwd,
                                        __ATOMIC_RELAXED, __HIP_MEMORY_SCOPE_AGENT);
        }

        // gather 3 partner row-slices: r8's proven wide self-validating poll
        {
            u32x4 vv;
            const unsigned* ap = hb + (gpj*JSL + gq*4);
            for (;;) {
                unsigned f = 0u;
                if (gp < 3) {
                    asm volatile(
                        "global_load_dwordx4 %0, %1, off sc0 sc1\n\t"
                        "s_waitcnt vmcnt(0)"
                        : "=v"(vv) : "v"(ap) : "memory");
                    f = ((vv[0]>>16)^tgt)|((vv[1]>>16)^tgt)
                      | ((vv[2]>>16)^tgt)|((vv[3]>>16)^tgt);
                }
                if (!__any(f != 0u)) break;
            }
            if (gp < 3) {
                const int c0 = NIN + gpj*JSL + gq*4;
                const unsigned d0 = (vv[0] & 0xFFFFu) | (vv[1] << 16);
                const unsigned d1 = (vv[2] & 0xFFFFu) | (vv[3] << 16);
                *(unsigned long long*)(anx + w*ROWB + ((c0*2) ^ (w << 4))) =
                    ((unsigned long long)d1 << 32) | (unsigned long long)d0;
            }
        }

        __syncthreads();   // B2: anx complete for next step
    }

    // ---- final FC: lane holds h(prow, jw*64+pj); reduce j4 quads ----
    {
        float v = Wfc[jw*JSL + pj] * hlast;
        v += __shfl_xor(v, 1);
        v += __shfl_xor(v, 2);
        if (j4 == 0) {
            if (jw == 0 && w == 0) v += bfc[0];
            atomicAdd(&out[cb + prow], v);
        }
    }
}

extern "C" void kernel_launch(void* const* d_in, const int* in_sizes, int n_in,
                              void* d_out, int out_size, void* d_ws, size_t ws_size,
                              hipStream_t stream)
{
    const float* x   = (const float*)d_in[0];
    const float* Wih = (const float*)d_in[1];
    const float* Whh = (const float*)d_in[2];
    const float* bih = (const float*)d_in[3];
    const float* bhh = (const float*)d_in[4];
    const float* Wfc = (const float*)d_in[5];
    const float* bfc = (const float*)d_in[6];
    float* out = (float*)d_out;

    unsigned* hq = (unsigned*)d_ws;   // [2][256][256] tagged words

    hipMemsetAsync(hq, 0, (size_t)2*B_TOT*HID*sizeof(unsigned), stream);
    hipMemsetAsync(d_out, 0, out_size*sizeof(float), stream);
    lstm_scan<<<NWG, 1024, 0, stream>>>(x, Wih, Whh, bih, bhh, Wfc, bfc,
                                        out, hq);
}